// Round 3
// baseline (61.647 us; speedup 1.0000x reference)
//
#include <hip/hip_runtime.h>

#define Bt 32768
#define Dt 64
#define St 16
#define Ht 128
#define At 17

typedef __attribute__((ext_vector_type(8))) short bf16x8;
typedef __attribute__((ext_vector_type(4))) float f32x4;

// ---- workspace layout (bytes) ----
#define CNT_OFF   0          // int[16]
#define PERM_OFF  128        // u16 [S][B]  (1 MiB)
#define WB_OFF    1049600    // bf16 transposed weight images [n][k], NO swizzle
#define OA1 0        // Wa1^T: 128 rows x 128B (K=64)
#define OA2 16384    // Wa2^T: 128 rows x 256B (K=128)
#define OA3 49152    // Wa3^T: 32-row region, rows >=17 unused garbage
#define OC1 57344    // Wc1^T
#define OC2 73728    // Wc2^T
#define SKB 106496   // per-skill stride

__device__ __forceinline__ unsigned short f2bf(float f) {
  union { float f; unsigned u; } v; v.f = f;
  unsigned r = v.u + 0x7FFFu + ((v.u >> 16) & 1u);  // RNE
  return (unsigned short)(r >> 16);
}

__device__ __forceinline__ float fast_tanh(float x) {
  float t = __expf(2.0f * x);                 // inf-safe: t=inf -> 1, t=0 -> -1
  return 1.0f - __fdividef(2.0f, t + 1.0f);
}

__device__ __forceinline__ f32x4 MFMA(bf16x8 a, bf16x8 b, f32x4 c) {
  return __builtin_amdgcn_mfma_f32_16x16x32_bf16(a, b, c, 0, 0, 0);
}

// ---------- dispatch 2: fused bucket (blocks 80..207) + weight prep (blocks 0..79) ----------
__global__ __launch_bounds__(256) void k_fused(
    const int* __restrict__ sid, unsigned short* __restrict__ perm,
    int* __restrict__ cnt,
    const float* __restrict__ Wa1, const float* __restrict__ Wa2,
    const float* __restrict__ Wa3, const float* __restrict__ Wc1,
    const float* __restrict__ Wc2, char* __restrict__ G) {
  __shared__ __align__(16) char smem[32768];
  const int tid = threadIdx.x;
  const int bid = blockIdx.x;

  if (bid >= 80) {
    // ---- bucket role: scatter row ids into per-skill lists ----
    int* lc = (int*)smem;
    int* lb = lc + St;
    const int b = (bid - 80) * 256 + tid;
    if (tid < St) lc[tid] = 0;
    __syncthreads();
    const int s = sid[b];
    const int p = atomicAdd(&lc[s], 1);
    __syncthreads();
    if (tid < St) lb[tid] = atomicAdd(&cnt[tid], lc[tid]);
    __syncthreads();
    perm[s * Bt + lb[s] + p] = (unsigned short)b;
    return;
  }

  // ---- prep role: fp32 [k][n] -> bf16 [n][k] image, via LDS transpose ----
  const int s = bid / 5, m = bid % 5;
  char* Gs = G + s * SKB;

  if (m == 2) {  // Wa3: 128x17, small & irregular -> direct scatter
    const float* src = Wa3 + s * Ht * At;
    for (int e = tid; e < Ht * At; e += 256) {
      const int k = e / At, n = e - k * At;
      *(unsigned short*)(Gs + OA3 + n * 256 + 2 * k) = f2bf(src[e]);
    }
    return;
  }

  const float* src; int K, off;
  if (m == 0)      { src = Wa1 + s * Dt * Ht; K = 64;  off = OA1; }
  else if (m == 1) { src = Wa2 + s * Ht * Ht; K = 128; off = OA2; }
  else if (m == 3) { src = Wc1 + s * Dt * Ht; K = 64;  off = OC1; }
  else             { src = Wc2 + s * Ht * Ht; K = 128; off = OC2; }
  const int SB = 2 * K;                 // image row bytes
  const int lsb = (K == 128) ? 8 : 7;
  const int pm = (K == 128) ? 15 : 7;   // prep-local XOR swizzle mask (bank spread)

  unsigned short* lds = (unsigned short*)smem;
  // phase 1: coalesced f32x4 reads along n; transposed, P_n-swizzled LDS writes
  for (int it = 0; it < K / 8; ++it) {
    const int f = (it * 256 + tid) * 4;  // flat float index, src is [k][128]
    const int k = f >> 7, n0 = f & 127;
    const f32x4 v = *(const f32x4*)(src + f);
#pragma unroll
    for (int j = 0; j < 4; ++j) {
      const int n = n0 + j;
      const int byte = n * SB + ((2 * k) ^ (((n >> 2) & pm) << 4));
      lds[byte >> 1] = f2bf(v[j]);
    }
  }
  __syncthreads();
  // phase 2: un-swizzled readout (2-way max), fully coalesced 8B global writes
  const int nbytes = 128 * SB;
  for (int it = 0; it < nbytes / 2048; ++it) {
    const int q = (it * 256 + tid) * 8;
    const int n = q >> lsb, r = q & (SB - 1);
    const unsigned long long v8 =
        *(const unsigned long long*)(smem + n * SB + (r ^ (((n >> 2) & pm) << 4)));
    *(unsigned long long*)(Gs + off + q) = v8;
  }
}

// ---------- dispatch 3: per-skill MLP. 8 waves = 2 row-groups x 4 col-groups ----------
__global__ __launch_bounds__(512, 6) void k_main(
    const float* __restrict__ obs,
    const float* __restrict__ ba1, const float* __restrict__ ba2,
    const float* __restrict__ ba3, const float* __restrict__ bc1,
    const float* __restrict__ bc2, const float* __restrict__ Wc3,
    const float* __restrict__ bc3,
    const int* __restrict__ cnt, const unsigned short* __restrict__ perm,
    const char* __restrict__ G, float* __restrict__ out) {
  __shared__ char hA[8192];        // 32 rows x 256B bf16 activations (ping)
  __shared__ char hB[8192];        // (pong)
  __shared__ float vbuf[32][4];    // value partials per col-group

  const int s = blockIdx.y;
  const int count = cnt[s];
  const int base = blockIdx.x * 32;
  if (base >= count) return;

  const int tid = threadIdx.x;
  const int wave = tid >> 6, lane = tid & 63;
  const int rg = wave >> 2, cg = wave & 3;       // row-group, col-group
  const int lr = lane & 15, lg = lane >> 4;
  const int cm1 = count - 1 - base;              // clamp limit, >= 0 here

  const unsigned short* ps = perm + s * Bt + base;
  const int myrow = ps[min(rg * 16 + lr, cm1)];  // tail entries are stale: clamp
  int orow[4]; bool oval[4];
#pragma unroll
  for (int i = 0; i < 4; ++i) {
    const int r = rg * 16 + lg * 4 + i;
    oval[i] = (r <= cm1);
    orow[i] = ps[min(r, cm1)];
  }

  // layer-1 A fragments from gathered obs rows (shared by actor & critic)
  const float* ap = obs + myrow * Dt + lg * 8;
  const f32x4 x0 = *(const f32x4*)(ap);
  const f32x4 x1 = *(const f32x4*)(ap + 4);
  const f32x4 x2 = *(const f32x4*)(ap + 32);
  const f32x4 x3 = *(const f32x4*)(ap + 36);
  bf16x8 a0, a1;
#pragma unroll
  for (int j = 0; j < 4; ++j) {
    a0[j] = (short)f2bf(x0[j]); a0[4 + j] = (short)f2bf(x1[j]);
    a1[j] = (short)f2bf(x2[j]); a1[4 + j] = (short)f2bf(x3[j]);
  }

  const char* Gs = G + s * SKB;
  const int hr = rg * 16 + lr;          // own LDS row for A-frag reads
  const int hsw = (hr & 7) << 4;

  // ================= actor layer 1 -> hA =================
#pragma unroll
  for (int nt = 0; nt < 2; ++nt) {
    const int n = cg * 32 + nt * 16 + lr;
    const char* wrow = Gs + OA1 + n * 128;
    const bf16x8 b0 = *(const bf16x8*)(wrow + lg * 16);
    const bf16x8 b1 = *(const bf16x8*)(wrow + 64 + lg * 16);
    f32x4 acc = {0.f, 0.f, 0.f, 0.f};
    acc = MFMA(a0, b0, acc);
    acc = MFMA(a1, b1, acc);
    const float bias = ba1[s * Ht + n];
#pragma unroll
    for (int i = 0; i < 4; ++i) {
      const int row = rg * 16 + lg * 4 + i;   // C/D: col=lane&15, row=(lane>>4)*4+i
      *(unsigned short*)(hA + row * 256 + ((2 * n) ^ ((row & 7) << 4))) =
          f2bf(fast_tanh(acc[i] + bias));
    }
  }
  __syncthreads();

  // ================= actor layer 2 -> hB =================
  {
    const char* hrow = hA + hr * 256;
    const bf16x8 A0 = *(const bf16x8*)(hrow + ((0   + lg * 16) ^ hsw));
    const bf16x8 A1 = *(const bf16x8*)(hrow + ((64  + lg * 16) ^ hsw));
    const bf16x8 A2 = *(const bf16x8*)(hrow + ((128 + lg * 16) ^ hsw));
    const bf16x8 A3 = *(const bf16x8*)(hrow + ((192 + lg * 16) ^ hsw));
#pragma unroll
    for (int nt = 0; nt < 2; ++nt) {
      const int n = cg * 32 + nt * 16 + lr;
      const char* wrow = Gs + OA2 + n * 256;
      f32x4 acc = {0.f, 0.f, 0.f, 0.f};
      acc = MFMA(A0, *(const bf16x8*)(wrow + lg * 16), acc);
      acc = MFMA(A1, *(const bf16x8*)(wrow + 64 + lg * 16), acc);
      acc = MFMA(A2, *(const bf16x8*)(wrow + 128 + lg * 16), acc);
      acc = MFMA(A3, *(const bf16x8*)(wrow + 192 + lg * 16), acc);
      const float bias = ba2[s * Ht + n];
#pragma unroll
      for (int i = 0; i < 4; ++i) {
        const int row = rg * 16 + lg * 4 + i;
        *(unsigned short*)(hB + row * 256 + ((2 * n) ^ ((row & 7) << 4))) =
            f2bf(fast_tanh(acc[i] + bias));
      }
    }
  }
  __syncthreads();

  // ======== actor layer 3 (cg 0,1 only) -> logits; critic layer 1 (all) -> hA ========
  if (cg < 2) {
    const char* hrow = hB + hr * 256;
    const bf16x8 H0 = *(const bf16x8*)(hrow + ((0   + lg * 16) ^ hsw));
    const bf16x8 H1 = *(const bf16x8*)(hrow + ((64  + lg * 16) ^ hsw));
    const bf16x8 H2 = *(const bf16x8*)(hrow + ((128 + lg * 16) ^ hsw));
    const bf16x8 H3 = *(const bf16x8*)(hrow + ((192 + lg * 16) ^ hsw));
    const int n = cg * 16 + lr;          // 0..31; cols 17..31 garbage, discarded
    const char* wrow = Gs + OA3 + n * 256;
    f32x4 acc = {0.f, 0.f, 0.f, 0.f};
    acc = MFMA(H0, *(const bf16x8*)(wrow + lg * 16), acc);
    acc = MFMA(H1, *(const bf16x8*)(wrow + 64 + lg * 16), acc);
    acc = MFMA(H2, *(const bf16x8*)(wrow + 128 + lg * 16), acc);
    acc = MFMA(H3, *(const bf16x8*)(wrow + 192 + lg * 16), acc);
    if (n < At) {
      const float bias = ba3[s * At + n];
#pragma unroll
      for (int i = 0; i < 4; ++i) {
        if (oval[i]) out[orow[i] * At + n] = acc[i] + bias;
      }
    }
  }
#pragma unroll
  for (int nt = 0; nt < 2; ++nt) {       // critic layer 1 (a0,a1 still live)
    const int n = cg * 32 + nt * 16 + lr;
    const char* wrow = Gs + OC1 + n * 128;
    const bf16x8 b0 = *(const bf16x8*)(wrow + lg * 16);
    const bf16x8 b1 = *(const bf16x8*)(wrow + 64 + lg * 16);
    f32x4 acc = {0.f, 0.f, 0.f, 0.f};
    acc = MFMA(a0, b0, acc);
    acc = MFMA(a1, b1, acc);
    const float bias = bc1[s * Ht + n];
#pragma unroll
    for (int i = 0; i < 4; ++i) {
      const int row = rg * 16 + lg * 4 + i;
      *(unsigned short*)(hA + row * 256 + ((2 * n) ^ ((row & 7) << 4))) =
          f2bf(fast_tanh(acc[i] + bias));
    }
  }
  __syncthreads();

  // ================= critic layer 2 + value partials =================
  {
    const char* hrow = hA + hr * 256;
    const bf16x8 A0 = *(const bf16x8*)(hrow + ((0   + lg * 16) ^ hsw));
    const bf16x8 A1 = *(const bf16x8*)(hrow + ((64  + lg * 16) ^ hsw));
    const bf16x8 A2 = *(const bf16x8*)(hrow + ((128 + lg * 16) ^ hsw));
    const bf16x8 A3 = *(const bf16x8*)(hrow + ((192 + lg * 16) ^ hsw));
    float vp0 = 0.f, vp1 = 0.f, vp2 = 0.f, vp3 = 0.f;
#pragma unroll
    for (int nt = 0; nt < 2; ++nt) {
      const int n = cg * 32 + nt * 16 + lr;
      const char* wrow = Gs + OC2 + n * 256;
      f32x4 acc = {0.f, 0.f, 0.f, 0.f};
      acc = MFMA(A0, *(const bf16x8*)(wrow + lg * 16), acc);
      acc = MFMA(A1, *(const bf16x8*)(wrow + 64 + lg * 16), acc);
      acc = MFMA(A2, *(const bf16x8*)(wrow + 128 + lg * 16), acc);
      acc = MFMA(A3, *(const bf16x8*)(wrow + 192 + lg * 16), acc);
      const float bias = bc2[s * Ht + n];
      const float w3 = Wc3[s * Ht + n];
      vp0 += fast_tanh(acc[0] + bias) * w3;
      vp1 += fast_tanh(acc[1] + bias) * w3;
      vp2 += fast_tanh(acc[2] + bias) * w3;
      vp3 += fast_tanh(acc[3] + bias) * w3;
    }
#pragma unroll
    for (int d = 1; d < 16; d <<= 1) {   // reduce the 16 cols this lane-group holds
      vp0 += __shfl_xor(vp0, d);
      vp1 += __shfl_xor(vp1, d);
      vp2 += __shfl_xor(vp2, d);
      vp3 += __shfl_xor(vp3, d);
    }
    if (lr == 0) {
      vbuf[rg * 16 + lg * 4 + 0][cg] = vp0;
      vbuf[rg * 16 + lg * 4 + 1][cg] = vp1;
      vbuf[rg * 16 + lg * 4 + 2][cg] = vp2;
      vbuf[rg * 16 + lg * 4 + 3][cg] = vp3;
    }
  }
  __syncthreads();
  if (tid < 32) {
    const int row = tid;
    if (row <= cm1) {
      const float v = vbuf[row][0] + vbuf[row][1] + vbuf[row][2] + vbuf[row][3];
      out[Bt * At + ps[row]] = v + bc3[s];
    }
  }
}

extern "C" void kernel_launch(void* const* d_in, const int* in_sizes, int n_in,
                              void* d_out, int out_size, void* d_ws, size_t ws_size,
                              hipStream_t stream) {
  const float* obs = (const float*)d_in[0];
  const int* sid   = (const int*)d_in[1];
  const float* Wa1 = (const float*)d_in[2];
  const float* ba1 = (const float*)d_in[3];
  const float* Wa2 = (const float*)d_in[4];
  const float* ba2 = (const float*)d_in[5];
  const float* Wa3 = (const float*)d_in[6];
  const float* ba3 = (const float*)d_in[7];
  const float* Wc1 = (const float*)d_in[8];
  const float* bc1 = (const float*)d_in[9];
  const float* Wc2 = (const float*)d_in[10];
  const float* bc2 = (const float*)d_in[11];
  const float* Wc3 = (const float*)d_in[12];
  const float* bc3 = (const float*)d_in[13];
  float* out = (float*)d_out;
  char* ws = (char*)d_ws;

  int* cnt = (int*)(ws + CNT_OFF);
  unsigned short* perm = (unsigned short*)(ws + PERM_OFF);
  char* G = ws + WB_OFF;

  hipMemsetAsync(cnt, 0, St * sizeof(int), stream);
  k_fused<<<dim3(208), dim3(256), 0, stream>>>(sid, perm, cnt, Wa1, Wa2, Wa3, Wc1, Wc2, G);
  k_main<<<dim3(Bt / 32, St), dim3(512), 0, stream>>>(
      obs, ba1, ba2, ba3, bc1, bc2, Wc3, bc3, cnt, perm, G, out);
}

// Round 4
// 58.126 us; speedup vs baseline: 1.0606x; 1.0606x over previous
//
#include <hip/hip_runtime.h>

#define Bt 32768
#define Dt 64
#define St 16
#define Ht 128
#define At 17

typedef __attribute__((ext_vector_type(8))) short bf16x8;
typedef __attribute__((ext_vector_type(4))) float f32x4;

// ---- workspace layout (bytes) ----
#define CNT_OFF   0          // int[16]
#define PERM_OFF  128        // u16 [S][B]  (1 MiB)
#define WB_OFF    1049600    // bf16 transposed weight images [n][k]
#define OA1 0        // Wa1^T: 128 rows x 128B (K=64)
#define OA2 16384    // Wa2^T: 128 rows x 256B (K=128)
#define OA3 49152    // Wa3^T: 32-row region, rows >=17 unused garbage
#define OC1 57344    // Wc1^T
#define OC2 73728    // Wc2^T
#define SKB 106496   // per-skill stride

__device__ __forceinline__ unsigned short f2bf(float f) {
  union { float f; unsigned u; } v; v.f = f;
  unsigned r = v.u + 0x7FFFu + ((v.u >> 16) & 1u);  // RNE
  return (unsigned short)(r >> 16);
}

__device__ __forceinline__ unsigned pk2(float a, float b) {  // (b<<16)|a as bf16 pair
  return (unsigned)f2bf(a) | ((unsigned)f2bf(b) << 16);
}

__device__ __forceinline__ float fast_tanh(float x) {
  float t = __expf(2.0f * x);                 // inf-safe: t=inf -> 1, t=0 -> -1
  return 1.0f - __fdividef(2.0f, t + 1.0f);
}

__device__ __forceinline__ f32x4 MFMA(bf16x8 a, bf16x8 b, f32x4 c) {
  return __builtin_amdgcn_mfma_f32_16x16x32_bf16(a, b, c, 0, 0, 0);
}

// intra-wave LDS RAW/WAR fence (hbuf slices are wave-private; no __syncthreads)
#define LGKM0() asm volatile("s_waitcnt lgkmcnt(0)" ::: "memory")

// ---------- dispatch 2: fused bucket (blocks 80..207) + weight prep (blocks 0..79) ----------
__global__ __launch_bounds__(256) void k_fused(
    const int* __restrict__ sid, unsigned short* __restrict__ perm,
    int* __restrict__ cnt,
    const float* __restrict__ Wa1, const float* __restrict__ Wa2,
    const float* __restrict__ Wa3, const float* __restrict__ Wc1,
    const float* __restrict__ Wc2, char* __restrict__ G) {
  __shared__ __align__(16) char smem[32768];
  const int tid = threadIdx.x;
  const int bid = blockIdx.x;

  if (bid >= 80) {
    int* lc = (int*)smem;
    int* lb = lc + St;
    const int b = (bid - 80) * 256 + tid;
    if (tid < St) lc[tid] = 0;
    __syncthreads();
    const int s = sid[b];
    const int p = atomicAdd(&lc[s], 1);
    __syncthreads();
    if (tid < St) lb[tid] = atomicAdd(&cnt[tid], lc[tid]);
    __syncthreads();
    perm[s * Bt + lb[s] + p] = (unsigned short)b;
    return;
  }

  const int s = bid / 5, m = bid % 5;
  char* Gs = G + s * SKB;

  if (m == 2) {  // Wa3: 128x17 -> direct scatter
    const float* src = Wa3 + s * Ht * At;
    for (int e = tid; e < Ht * At; e += 256) {
      const int k = e / At, n = e - k * At;
      *(unsigned short*)(Gs + OA3 + n * 256 + 2 * k) = f2bf(src[e]);
    }
    return;
  }

  const float* src; int K, off;
  if (m == 0)      { src = Wa1 + s * Dt * Ht; K = 64;  off = OA1; }
  else if (m == 1) { src = Wa2 + s * Ht * Ht; K = 128; off = OA2; }
  else if (m == 3) { src = Wc1 + s * Dt * Ht; K = 64;  off = OC1; }
  else             { src = Wc2 + s * Ht * Ht; K = 128; off = OC2; }
  const int SB = 2 * K;
  const int lsb = (K == 128) ? 8 : 7;
  const int pm = (K == 128) ? 15 : 7;

  unsigned short* lds = (unsigned short*)smem;
  for (int it = 0; it < K / 8; ++it) {
    const int f = (it * 256 + tid) * 4;
    const int k = f >> 7, n0 = f & 127;
    const f32x4 v = *(const f32x4*)(src + f);
#pragma unroll
    for (int j = 0; j < 4; ++j) {
      const int n = n0 + j;
      const int byte = n * SB + ((2 * k) ^ (((n >> 2) & pm) << 4));
      lds[byte >> 1] = f2bf(v[j]);
    }
  }
  __syncthreads();
  const int nbytes = 128 * SB;
  for (int it = 0; it < nbytes / 2048; ++it) {
    const int q = (it * 256 + tid) * 8;
    const int n = q >> lsb, r = q & (SB - 1);
    const unsigned long long v8 =
        *(const unsigned long long*)(smem + n * SB + (r ^ (((n >> 2) & pm) << 4)));
    *(unsigned long long*)(Gs + off + q) = v8;
  }
}

// ---------- dispatch 3: swapped-operand MLP; 4 waves x 16 rows, barrier-free ----------
__global__ __launch_bounds__(256, 4) void k_main(
    const float* __restrict__ obs,
    const float* __restrict__ ba1, const float* __restrict__ ba2,
    const float* __restrict__ ba3, const float* __restrict__ bc1,
    const float* __restrict__ bc2, const float* __restrict__ Wc3,
    const float* __restrict__ bc3,
    const int* __restrict__ cnt, const unsigned short* __restrict__ perm,
    const char* __restrict__ G, float* __restrict__ out) {
  __shared__ char hbuf[16384];   // 4 waves x (16 rows x 256B), wave-private slices

  const int tid = threadIdx.x;
  const int wave = tid >> 6, lane = tid & 63;
  const int m = lane & 15, lg = lane >> 4;
  const int bid = blockIdx.x;

  // ---- tile lookup: in-wave prefix scan over cnt (no dead blocks) ----
  const int c16 = cnt[m];                 // all four 16-lane groups identical
  const int t16 = (c16 + 63) >> 6;
  int incl = t16;
#pragma unroll
  for (int d = 1; d < 16; d <<= 1) {
    const int o = __shfl_up(incl, d, 16);
    if (m >= d) incl += o;
  }
  const int total = __shfl(incl, 15, 16);
  if (bid >= total) return;
  const int excl = incl - t16;
  const unsigned long long ball = __ballot(excl <= bid);
  const int s = (int)(__popcll(ball) >> 2) - 1;
  const int excl_s = __shfl(excl, s, 16);
  const int cs = __shfl(c16, s, 16);
  const int base = (bid - excl_s) * 64;
  const int cm1 = cs - 1 - base;          // >= 0

  const unsigned short* ps = perm + s * Bt + base;
  const int myrow = ps[min(wave * 16 + m, cm1)];   // clamped tail: dup rows, same values

  // ---- obs B-fragments (lane col = its own row m) ----
  const float* ap = obs + myrow * Dt + lg * 8;
  const f32x4 x0 = *(const f32x4*)(ap);
  const f32x4 x1 = *(const f32x4*)(ap + 4);
  const f32x4 x2 = *(const f32x4*)(ap + 32);
  const f32x4 x3 = *(const f32x4*)(ap + 36);
  bf16x8 xB0, xB1;
#pragma unroll
  for (int j = 0; j < 4; ++j) {
    xB0[j] = (short)f2bf(x0[j]); xB0[4 + j] = (short)f2bf(x1[j]);
    xB1[j] = (short)f2bf(x2[j]); xB1[4 + j] = (short)f2bf(x3[j]);
  }

  const char* Gs = G + s * SKB;
  char* hw = hbuf + wave * 4096 + m * 256;   // my row's LDS line
  const int msw = (m & 7) << 4;

  // ================= actor layer 1 (D = Wa1^T x^T -> lane holds h[m][32 cols]) ====
#pragma unroll
  for (int t = 0; t < 8; ++t) {
    const char* wr = Gs + OA1 + (t * 16 + m) * 128 + lg * 16;  // A: row n=16t+m, k=8lg+j
    f32x4 acc = {0.f, 0.f, 0.f, 0.f};
    acc = MFMA(*(const bf16x8*)(wr), xB0, acc);
    acc = MFMA(*(const bf16x8*)(wr + 64), xB1, acc);
    const f32x4 bias = *(const f32x4*)(ba1 + s * Ht + t * 16 + lg * 4);
    const unsigned lo = pk2(fast_tanh(acc[0] + bias[0]), fast_tanh(acc[1] + bias[1]));
    const unsigned hi = pk2(fast_tanh(acc[2] + bias[2]), fast_tanh(acc[3] + bias[3]));
    *(unsigned long long*)(hw + ((32 * t + 8 * lg) ^ msw)) =
        (unsigned long long)lo | ((unsigned long long)hi << 32);
  }
  LGKM0();

  // ================= actor layer 2 =================
  {
    const bf16x8 h0 = *(const bf16x8*)(hw + ((0   + 16 * lg) ^ msw));
    const bf16x8 h1 = *(const bf16x8*)(hw + ((64  + 16 * lg) ^ msw));
    const bf16x8 h2 = *(const bf16x8*)(hw + ((128 + 16 * lg) ^ msw));
    const bf16x8 h3 = *(const bf16x8*)(hw + ((192 + 16 * lg) ^ msw));
    LGKM0();   // reads complete before overwrites below
#pragma unroll
    for (int t = 0; t < 8; ++t) {
      const char* wr = Gs + OA2 + (t * 16 + m) * 256 + lg * 16;
      f32x4 acc = {0.f, 0.f, 0.f, 0.f};
      acc = MFMA(*(const bf16x8*)(wr), h0, acc);
      acc = MFMA(*(const bf16x8*)(wr + 64), h1, acc);
      acc = MFMA(*(const bf16x8*)(wr + 128), h2, acc);
      acc = MFMA(*(const bf16x8*)(wr + 192), h3, acc);
      const f32x4 bias = *(const f32x4*)(ba2 + s * Ht + t * 16 + lg * 4);
      const unsigned lo = pk2(fast_tanh(acc[0] + bias[0]), fast_tanh(acc[1] + bias[1]));
      const unsigned hi = pk2(fast_tanh(acc[2] + bias[2]), fast_tanh(acc[3] + bias[3]));
      *(unsigned long long*)(hw + ((32 * t + 8 * lg) ^ msw)) =
          (unsigned long long)lo | ((unsigned long long)hi << 32);
    }
  }
  LGKM0();

  // ================= actor layer 3 -> logits =================
  {
    const bf16x8 h0 = *(const bf16x8*)(hw + ((0   + 16 * lg) ^ msw));
    const bf16x8 h1 = *(const bf16x8*)(hw + ((64  + 16 * lg) ^ msw));
    const bf16x8 h2 = *(const bf16x8*)(hw + ((128 + 16 * lg) ^ msw));
    const bf16x8 h3 = *(const bf16x8*)(hw + ((192 + 16 * lg) ^ msw));
    LGKM0();   // reads complete before critic L1 overwrites
    f32x4 acc0 = {0.f, 0.f, 0.f, 0.f}, acc1 = {0.f, 0.f, 0.f, 0.f};
    {
      const char* wr = Gs + OA3 + m * 256 + lg * 16;          // t=0: n=m
      acc0 = MFMA(*(const bf16x8*)(wr), h0, acc0);
      acc0 = MFMA(*(const bf16x8*)(wr + 64), h1, acc0);
      acc0 = MFMA(*(const bf16x8*)(wr + 128), h2, acc0);
      acc0 = MFMA(*(const bf16x8*)(wr + 192), h3, acc0);
    }
    {
      const char* wr = Gs + OA3 + (16 + m) * 256 + lg * 16;   // t=1: n=16+m (only n=16 kept)
      acc1 = MFMA(*(const bf16x8*)(wr), h0, acc1);
      acc1 = MFMA(*(const bf16x8*)(wr + 64), h1, acc1);
      acc1 = MFMA(*(const bf16x8*)(wr + 128), h2, acc1);
      acc1 = MFMA(*(const bf16x8*)(wr + 192), h3, acc1);
    }
    float* orow = out + myrow * At;
#pragma unroll
    for (int i = 0; i < 4; ++i)                 // n = 4lg+i, 0..15
      orow[4 * lg + i] = acc0[i] + ba3[s * At + 4 * lg + i];
    if (lg == 0) orow[16] = acc1[0] + ba3[s * At + 16];   // n = 16
  }

  // ================= critic layer 1 (xB still live) =================
#pragma unroll
  for (int t = 0; t < 8; ++t) {
    const char* wr = Gs + OC1 + (t * 16 + m) * 128 + lg * 16;
    f32x4 acc = {0.f, 0.f, 0.f, 0.f};
    acc = MFMA(*(const bf16x8*)(wr), xB0, acc);
    acc = MFMA(*(const bf16x8*)(wr + 64), xB1, acc);
    const f32x4 bias = *(const f32x4*)(bc1 + s * Ht + t * 16 + lg * 4);
    const unsigned lo = pk2(fast_tanh(acc[0] + bias[0]), fast_tanh(acc[1] + bias[1]));
    const unsigned hi = pk2(fast_tanh(acc[2] + bias[2]), fast_tanh(acc[3] + bias[3]));
    *(unsigned long long*)(hw + ((32 * t + 8 * lg) ^ msw)) =
        (unsigned long long)lo | ((unsigned long long)hi << 32);
  }
  LGKM0();

  // ================= critic layer 2 + value =================
  {
    const bf16x8 h0 = *(const bf16x8*)(hw + ((0   + 16 * lg) ^ msw));
    const bf16x8 h1 = *(const bf16x8*)(hw + ((64  + 16 * lg) ^ msw));
    const bf16x8 h2 = *(const bf16x8*)(hw + ((128 + 16 * lg) ^ msw));
    const bf16x8 h3 = *(const bf16x8*)(hw + ((192 + 16 * lg) ^ msw));
    float vp = 0.f;
#pragma unroll
    for (int t = 0; t < 8; ++t) {
      const char* wr = Gs + OC2 + (t * 16 + m) * 256 + lg * 16;
      f32x4 acc = {0.f, 0.f, 0.f, 0.f};
      acc = MFMA(*(const bf16x8*)(wr), h0, acc);
      acc = MFMA(*(const bf16x8*)(wr + 64), h1, acc);
      acc = MFMA(*(const bf16x8*)(wr + 128), h2, acc);
      acc = MFMA(*(const bf16x8*)(wr + 192), h3, acc);
      const f32x4 bias = *(const f32x4*)(bc2 + s * Ht + t * 16 + lg * 4);
      const f32x4 w3   = *(const f32x4*)(Wc3 + s * Ht + t * 16 + lg * 4);
#pragma unroll
      for (int i = 0; i < 4; ++i)
        vp += fast_tanh(acc[i] + bias[i]) * w3[i];
    }
    vp += __shfl_xor(vp, 16);     // reduce across the 4 lane-groups sharing row m
    vp += __shfl_xor(vp, 32);
    if (lane < 16) out[Bt * At + myrow] = vp + bc3[s];
  }
}

extern "C" void kernel_launch(void* const* d_in, const int* in_sizes, int n_in,
                              void* d_out, int out_size, void* d_ws, size_t ws_size,
                              hipStream_t stream) {
  const float* obs = (const float*)d_in[0];
  const int* sid   = (const int*)d_in[1];
  const float* Wa1 = (const float*)d_in[2];
  const float* ba1 = (const float*)d_in[3];
  const float* Wa2 = (const float*)d_in[4];
  const float* ba2 = (const float*)d_in[5];
  const float* Wa3 = (const float*)d_in[6];
  const float* ba3 = (const float*)d_in[7];
  const float* Wc1 = (const float*)d_in[8];
  const float* bc1 = (const float*)d_in[9];
  const float* Wc2 = (const float*)d_in[10];
  const float* bc2 = (const float*)d_in[11];
  const float* Wc3 = (const float*)d_in[12];
  const float* bc3 = (const float*)d_in[13];
  float* out = (float*)d_out;
  char* ws = (char*)d_ws;

  int* cnt = (int*)(ws + CNT_OFF);
  unsigned short* perm = (unsigned short*)(ws + PERM_OFF);
  char* G = ws + WB_OFF;

  hipMemsetAsync(cnt, 0, St * sizeof(int), stream);
  k_fused<<<dim3(208), dim3(256), 0, stream>>>(sid, perm, cnt, Wa1, Wa2, Wa3, Wc1, Wc2, G);
  k_main<<<dim3(528), dim3(256), 0, stream>>>(
      obs, ba1, ba2, ba3, bc1, bc2, Wc3, bc3, cnt, perm, G, out);
}

// Round 5
// 54.421 us; speedup vs baseline: 1.1328x; 1.0681x over previous
//
#include <hip/hip_runtime.h>

#define Bt 32768
#define Dt 64
#define St 16
#define Ht 128
#define At 17

typedef __attribute__((ext_vector_type(8))) short bf16x8;
typedef __attribute__((ext_vector_type(4))) float f32x4;

// ---- workspace layout (bytes) ----
#define CNT_OFF   0          // int[16]
#define PERM_OFF  128        // u16 [S][B]  (1 MiB)
#define WB_OFF    1049600    // bf16 transposed weight images [n][k]
#define OA1 0        // Wa1^T: 128 rows x 128B (K=64)
#define OA2 16384    // Wa2^T: 128 rows x 256B (K=128)
#define OA3 49152    // Wa3^T: 32-row region, rows >=17 unused garbage
#define OC1 57344    // Wc1^T
#define OC2 73728    // Wc2^T
#define SKB 106496   // per-skill stride

__device__ __forceinline__ unsigned short f2bf(float f) {
  union { float f; unsigned u; } v; v.f = f;
  unsigned r = v.u + 0x7FFFu + ((v.u >> 16) & 1u);  // RNE
  return (unsigned short)(r >> 16);
}

// packed f32x2 -> bf16x2 in one VALU op (gfx950 v_cvt_pk_bf16_f32; src0 -> lo)
__device__ __forceinline__ unsigned cvtpk(float a, float b) {
  unsigned r;
  asm("v_cvt_pk_bf16_f32 %0, %1, %2" : "=v"(r) : "v"(a), "v"(b));
  return r;
}

// tanh(acc + bias) with b2 = 2*bias precomputed: fma, mul+exp, add, rcp, fma
__device__ __forceinline__ float tanh_fb(float acc, float b2) {
  const float t = __expf(__builtin_fmaf(acc, 2.0f, b2));  // inf-safe
  const float r = __builtin_amdgcn_rcpf(t + 1.0f);
  return __builtin_fmaf(-2.0f, r, 1.0f);
}

__device__ __forceinline__ f32x4 MFMA(bf16x8 a, bf16x8 b, f32x4 c) {
  return __builtin_amdgcn_mfma_f32_16x16x32_bf16(a, b, c, 0, 0, 0);
}

// intra-wave LDS RAW/WAR fence (hbuf slices are wave-private; no __syncthreads)
#define LGKM0() asm volatile("s_waitcnt lgkmcnt(0)" ::: "memory")

// ---------- dispatch 2: fused bucket (blocks 80..207) + weight prep (blocks 0..79) ----------
__global__ __launch_bounds__(256) void k_fused(
    const int* __restrict__ sid, unsigned short* __restrict__ perm,
    int* __restrict__ cnt,
    const float* __restrict__ Wa1, const float* __restrict__ Wa2,
    const float* __restrict__ Wa3, const float* __restrict__ Wc1,
    const float* __restrict__ Wc2, char* __restrict__ G) {
  __shared__ __align__(16) char smem[32768];
  const int tid = threadIdx.x;
  const int bid = blockIdx.x;

  if (bid >= 80) {
    int* lc = (int*)smem;
    int* lb = lc + St;
    const int b = (bid - 80) * 256 + tid;
    if (tid < St) lc[tid] = 0;
    __syncthreads();
    const int s = sid[b];
    const int p = atomicAdd(&lc[s], 1);
    __syncthreads();
    if (tid < St) lb[tid] = atomicAdd(&cnt[tid], lc[tid]);
    __syncthreads();
    perm[s * Bt + lb[s] + p] = (unsigned short)b;
    return;
  }

  const int s = bid / 5, m = bid % 5;
  char* Gs = G + s * SKB;

  if (m == 2) {  // Wa3: 128x17 -> direct scatter
    const float* src = Wa3 + s * Ht * At;
    for (int e = tid; e < Ht * At; e += 256) {
      const int k = e / At, n = e - k * At;
      *(unsigned short*)(Gs + OA3 + n * 256 + 2 * k) = f2bf(src[e]);
    }
    return;
  }

  const float* src; int K, off;
  if (m == 0)      { src = Wa1 + s * Dt * Ht; K = 64;  off = OA1; }
  else if (m == 1) { src = Wa2 + s * Ht * Ht; K = 128; off = OA2; }
  else if (m == 3) { src = Wc1 + s * Dt * Ht; K = 64;  off = OC1; }
  else             { src = Wc2 + s * Ht * Ht; K = 128; off = OC2; }
  const int SB = 2 * K;
  const int lsb = (K == 128) ? 8 : 7;
  const int pm = (K == 128) ? 15 : 7;

  unsigned short* lds = (unsigned short*)smem;
  for (int it = 0; it < K / 8; ++it) {
    const int f = (it * 256 + tid) * 4;
    const int k = f >> 7, n0 = f & 127;
    const f32x4 v = *(const f32x4*)(src + f);
#pragma unroll
    for (int j = 0; j < 4; ++j) {
      const int n = n0 + j;
      const int byte = n * SB + ((2 * k) ^ (((n >> 2) & pm) << 4));
      lds[byte >> 1] = f2bf(v[j]);
    }
  }
  __syncthreads();
  const int nbytes = 128 * SB;
  for (int it = 0; it < nbytes / 2048; ++it) {
    const int q = (it * 256 + tid) * 8;
    const int n = q >> lsb, r = q & (SB - 1);
    const unsigned long long v8 =
        *(const unsigned long long*)(smem + n * SB + (r ^ (((n >> 2) & pm) << 4)));
    *(unsigned long long*)(Gs + off + q) = v8;
  }
}

// ---------- dispatch 3: swapped-operand MLP; actor/critic split across blocks ----------
// grid = (2 roles, 528 tiles); block = 4 waves x 16 rows; barrier-free.
__global__ __launch_bounds__(256, 4) void k_main(
    const float* __restrict__ obs,
    const float* __restrict__ ba1, const float* __restrict__ ba2,
    const float* __restrict__ ba3, const float* __restrict__ bc1,
    const float* __restrict__ bc2, const float* __restrict__ Wc3,
    const float* __restrict__ bc3,
    const int* __restrict__ cnt, const unsigned short* __restrict__ perm,
    const char* __restrict__ G, float* __restrict__ out) {
  __shared__ char hbuf[16384];   // 4 waves x (16 rows x 256B), wave-private slices

  const int tid = threadIdx.x;
  const int wave = tid >> 6, lane = tid & 63;
  const int m = lane & 15, lg = lane >> 4;
  const int bid = blockIdx.y;

  // ---- tile lookup: in-wave prefix scan over cnt (no dead blocks) ----
  const int c16 = cnt[m];                 // all four 16-lane groups identical
  const int t16 = (c16 + 63) >> 6;
  int incl = t16;
#pragma unroll
  for (int d = 1; d < 16; d <<= 1) {
    const int o = __shfl_up(incl, d, 16);
    if (m >= d) incl += o;
  }
  const int total = __shfl(incl, 15, 16);
  if (bid >= total) return;
  const int excl = incl - t16;
  const unsigned long long ball = __ballot(excl <= bid);
  const int s = (int)(__popcll(ball) >> 2) - 1;
  const int excl_s = __shfl(excl, s, 16);
  const int cs = __shfl(c16, s, 16);
  const int base = (bid - excl_s) * 64;
  const int cm1 = cs - 1 - base;          // >= 0

  const unsigned short* ps = perm + s * Bt + base;
  const int myrow = ps[min(wave * 16 + m, cm1)];   // clamped tail: dup rows, same values

  // ---- obs B-fragments (lane col = its own row m), packed via cvt_pk ----
  const float* ap = obs + myrow * Dt + lg * 8;
  const f32x4 x0 = *(const f32x4*)(ap);
  const f32x4 x1 = *(const f32x4*)(ap + 4);
  const f32x4 x2 = *(const f32x4*)(ap + 32);
  const f32x4 x3 = *(const f32x4*)(ap + 36);
  union { bf16x8 v; unsigned u[4]; } XB0, XB1;
  XB0.u[0] = cvtpk(x0[0], x0[1]); XB0.u[1] = cvtpk(x0[2], x0[3]);
  XB0.u[2] = cvtpk(x1[0], x1[1]); XB0.u[3] = cvtpk(x1[2], x1[3]);
  XB1.u[0] = cvtpk(x2[0], x2[1]); XB1.u[1] = cvtpk(x2[2], x2[3]);
  XB1.u[2] = cvtpk(x3[0], x3[1]); XB1.u[3] = cvtpk(x3[2], x3[3]);

  const char* Gs = G + s * SKB;
  char* hw = hbuf + wave * 4096 + m * 256;   // my row's LDS line
  const int msw = (m & 7) << 4;

  if (blockIdx.x == 0) {
    // =================== ACTOR: L1 -> L2 -> L3 ===================
#pragma unroll
    for (int t = 0; t < 8; ++t) {
      const char* wr = Gs + OA1 + (t * 16 + m) * 128 + lg * 16;
      f32x4 acc = {0.f, 0.f, 0.f, 0.f};
      acc = MFMA(*(const bf16x8*)(wr), XB0.v, acc);
      acc = MFMA(*(const bf16x8*)(wr + 64), XB1.v, acc);
      const f32x4 bias = *(const f32x4*)(ba1 + s * Ht + t * 16 + lg * 4);
      const f32x4 b2 = bias + bias;
      const unsigned lo = cvtpk(tanh_fb(acc[0], b2[0]), tanh_fb(acc[1], b2[1]));
      const unsigned hi = cvtpk(tanh_fb(acc[2], b2[2]), tanh_fb(acc[3], b2[3]));
      *(unsigned long long*)(hw + ((32 * t + 8 * lg) ^ msw)) =
          (unsigned long long)lo | ((unsigned long long)hi << 32);
    }
    LGKM0();
    {
      const bf16x8 h0 = *(const bf16x8*)(hw + ((0   + 16 * lg) ^ msw));
      const bf16x8 h1 = *(const bf16x8*)(hw + ((64  + 16 * lg) ^ msw));
      const bf16x8 h2 = *(const bf16x8*)(hw + ((128 + 16 * lg) ^ msw));
      const bf16x8 h3 = *(const bf16x8*)(hw + ((192 + 16 * lg) ^ msw));
      LGKM0();   // reads complete before overwrites below
#pragma unroll
      for (int t = 0; t < 8; ++t) {
        const char* wr = Gs + OA2 + (t * 16 + m) * 256 + lg * 16;
        f32x4 acc = {0.f, 0.f, 0.f, 0.f};
        acc = MFMA(*(const bf16x8*)(wr), h0, acc);
        acc = MFMA(*(const bf16x8*)(wr + 64), h1, acc);
        acc = MFMA(*(const bf16x8*)(wr + 128), h2, acc);
        acc = MFMA(*(const bf16x8*)(wr + 192), h3, acc);
        const f32x4 bias = *(const f32x4*)(ba2 + s * Ht + t * 16 + lg * 4);
        const f32x4 b2 = bias + bias;
        const unsigned lo = cvtpk(tanh_fb(acc[0], b2[0]), tanh_fb(acc[1], b2[1]));
        const unsigned hi = cvtpk(tanh_fb(acc[2], b2[2]), tanh_fb(acc[3], b2[3]));
        *(unsigned long long*)(hw + ((32 * t + 8 * lg) ^ msw)) =
            (unsigned long long)lo | ((unsigned long long)hi << 32);
      }
    }
    LGKM0();
    {
      const bf16x8 h0 = *(const bf16x8*)(hw + ((0   + 16 * lg) ^ msw));
      const bf16x8 h1 = *(const bf16x8*)(hw + ((64  + 16 * lg) ^ msw));
      const bf16x8 h2 = *(const bf16x8*)(hw + ((128 + 16 * lg) ^ msw));
      const bf16x8 h3 = *(const bf16x8*)(hw + ((192 + 16 * lg) ^ msw));
      f32x4 acc0 = {0.f, 0.f, 0.f, 0.f}, acc1 = {0.f, 0.f, 0.f, 0.f};
      {
        const char* wr = Gs + OA3 + m * 256 + lg * 16;          // n = m
        acc0 = MFMA(*(const bf16x8*)(wr), h0, acc0);
        acc0 = MFMA(*(const bf16x8*)(wr + 64), h1, acc0);
        acc0 = MFMA(*(const bf16x8*)(wr + 128), h2, acc0);
        acc0 = MFMA(*(const bf16x8*)(wr + 192), h3, acc0);
      }
      {
        const char* wr = Gs + OA3 + (16 + m) * 256 + lg * 16;   // n = 16+m (keep n=16)
        acc1 = MFMA(*(const bf16x8*)(wr), h0, acc1);
        acc1 = MFMA(*(const bf16x8*)(wr + 64), h1, acc1);
        acc1 = MFMA(*(const bf16x8*)(wr + 128), h2, acc1);
        acc1 = MFMA(*(const bf16x8*)(wr + 192), h3, acc1);
      }
      float* orow = out + myrow * At;
#pragma unroll
      for (int i = 0; i < 4; ++i)                 // n = 4lg+i, 0..15
        orow[4 * lg + i] = acc0[i] + ba3[s * At + 4 * lg + i];
      if (lg == 0) orow[16] = acc1[0] + ba3[s * At + 16];
    }
  } else {
    // =================== CRITIC: C1 -> C2 + value ===================
#pragma unroll
    for (int t = 0; t < 8; ++t) {
      const char* wr = Gs + OC1 + (t * 16 + m) * 128 + lg * 16;
      f32x4 acc = {0.f, 0.f, 0.f, 0.f};
      acc = MFMA(*(const bf16x8*)(wr), XB0.v, acc);
      acc = MFMA(*(const bf16x8*)(wr + 64), XB1.v, acc);
      const f32x4 bias = *(const f32x4*)(bc1 + s * Ht + t * 16 + lg * 4);
      const f32x4 b2 = bias + bias;
      const unsigned lo = cvtpk(tanh_fb(acc[0], b2[0]), tanh_fb(acc[1], b2[1]));
      const unsigned hi = cvtpk(tanh_fb(acc[2], b2[2]), tanh_fb(acc[3], b2[3]));
      *(unsigned long long*)(hw + ((32 * t + 8 * lg) ^ msw)) =
          (unsigned long long)lo | ((unsigned long long)hi << 32);
    }
    LGKM0();
    {
      const bf16x8 h0 = *(const bf16x8*)(hw + ((0   + 16 * lg) ^ msw));
      const bf16x8 h1 = *(const bf16x8*)(hw + ((64  + 16 * lg) ^ msw));
      const bf16x8 h2 = *(const bf16x8*)(hw + ((128 + 16 * lg) ^ msw));
      const bf16x8 h3 = *(const bf16x8*)(hw + ((192 + 16 * lg) ^ msw));
      float vp = 0.f;
#pragma unroll
      for (int t = 0; t < 8; ++t) {
        const char* wr = Gs + OC2 + (t * 16 + m) * 256 + lg * 16;
        f32x4 acc = {0.f, 0.f, 0.f, 0.f};
        acc = MFMA(*(const bf16x8*)(wr), h0, acc);
        acc = MFMA(*(const bf16x8*)(wr + 64), h1, acc);
        acc = MFMA(*(const bf16x8*)(wr + 128), h2, acc);
        acc = MFMA(*(const bf16x8*)(wr + 192), h3, acc);
        const f32x4 bias = *(const f32x4*)(bc2 + s * Ht + t * 16 + lg * 4);
        const f32x4 b2 = bias + bias;
        const f32x4 w3 = *(const f32x4*)(Wc3 + s * Ht + t * 16 + lg * 4);
#pragma unroll
        for (int i = 0; i < 4; ++i)
          vp = __builtin_fmaf(tanh_fb(acc[i], b2[i]), w3[i], vp);
      }
      vp += __shfl_xor(vp, 16);     // reduce across the 4 lane-groups sharing row m
      vp += __shfl_xor(vp, 32);
      if (lane < 16) out[Bt * At + myrow] = vp + bc3[s];
    }
  }
}

extern "C" void kernel_launch(void* const* d_in, const int* in_sizes, int n_in,
                              void* d_out, int out_size, void* d_ws, size_t ws_size,
                              hipStream_t stream) {
  const float* obs = (const float*)d_in[0];
  const int* sid   = (const int*)d_in[1];
  const float* Wa1 = (const float*)d_in[2];
  const float* ba1 = (const float*)d_in[3];
  const float* Wa2 = (const float*)d_in[4];
  const float* ba2 = (const float*)d_in[5];
  const float* Wa3 = (const float*)d_in[6];
  const float* ba3 = (const float*)d_in[7];
  const float* Wc1 = (const float*)d_in[8];
  const float* bc1 = (const float*)d_in[9];
  const float* Wc2 = (const float*)d_in[10];
  const float* bc2 = (const float*)d_in[11];
  const float* Wc3 = (const float*)d_in[12];
  const float* bc3 = (const float*)d_in[13];
  float* out = (float*)d_out;
  char* ws = (char*)d_ws;

  int* cnt = (int*)(ws + CNT_OFF);
  unsigned short* perm = (unsigned short*)(ws + PERM_OFF);
  char* G = ws + WB_OFF;

  hipMemsetAsync(cnt, 0, St * sizeof(int), stream);
  k_fused<<<dim3(208), dim3(256), 0, stream>>>(sid, perm, cnt, Wa1, Wa2, Wa3, Wc1, Wc2, G);
  k_main<<<dim3(2, 528), dim3(256), 0, stream>>>(
      obs, ba1, ba2, ba3, bc1, bc2, Wc3, bc3, cnt, perm, G, out);
}

// Round 6
// 54.184 us; speedup vs baseline: 1.1377x; 1.0044x over previous
//
#include <hip/hip_runtime.h>

#define Bt 32768
#define Dt 64
#define St 16
#define Ht 128
#define At 17

typedef __attribute__((ext_vector_type(8))) short bf16x8;
typedef __attribute__((ext_vector_type(4))) float f32x4;

// ---- workspace layout (bytes) ----
#define CNT_OFF   0          // int[16]
#define PERM_OFF  128        // u16 [S][B]  (1 MiB)
#define WB_OFF    1049600    // bf16 transposed weight images [n][k]
#define OA1 0        // Wa1^T: 128 rows x 128B (K=64)
#define OA2 16384    // Wa2^T: 128 rows x 256B (K=128)
#define OA3 49152    // Wa3^T: 32-row region, rows >=17 unused garbage
#define OC1 57344    // Wc1^T
#define OC2 73728    // Wc2^T
#define SKB 106496   // per-skill stride

__device__ __forceinline__ unsigned short f2bf(float f) {
  union { float f; unsigned u; } v; v.f = f;
  unsigned r = v.u + 0x7FFFu + ((v.u >> 16) & 1u);  // RNE
  return (unsigned short)(r >> 16);
}

// packed f32x2 -> bf16x2 in one VALU op (gfx950 v_cvt_pk_bf16_f32; src0 -> lo)
__device__ __forceinline__ unsigned cvtpk(float a, float b) {
  unsigned r;
  asm("v_cvt_pk_bf16_f32 %0, %1, %2" : "=v"(r) : "v"(a), "v"(b));
  return r;
}

// tanh(acc + bias) with b2 = 2*bias precomputed: fma, exp, add, rcp, fma
__device__ __forceinline__ float tanh_fb(float acc, float b2) {
  const float t = __expf(__builtin_fmaf(acc, 2.0f, b2));  // inf-safe
  const float r = __builtin_amdgcn_rcpf(t + 1.0f);
  return __builtin_fmaf(-2.0f, r, 1.0f);
}

__device__ __forceinline__ f32x4 MFMA(bf16x8 a, bf16x8 b, f32x4 c) {
  return __builtin_amdgcn_mfma_f32_16x16x32_bf16(a, b, c, 0, 0, 0);
}

// intra-wave LDS RAW/WAR fence (hbuf slices are wave-private; no __syncthreads)
#define LGKM0() asm volatile("s_waitcnt lgkmcnt(0)" ::: "memory")

// ---------- dispatch 2: fused bucket (blocks 80..207) + weight prep (blocks 0..79) ----------
__global__ __launch_bounds__(256) void k_fused(
    const int* __restrict__ sid, unsigned short* __restrict__ perm,
    int* __restrict__ cnt,
    const float* __restrict__ Wa1, const float* __restrict__ Wa2,
    const float* __restrict__ Wa3, const float* __restrict__ Wc1,
    const float* __restrict__ Wc2, char* __restrict__ G) {
  __shared__ __align__(16) char smem[32768];
  const int tid = threadIdx.x;
  const int bid = blockIdx.x;

  if (bid >= 80) {
    int* lc = (int*)smem;
    int* lb = lc + St;
    const int b = (bid - 80) * 256 + tid;
    if (tid < St) lc[tid] = 0;
    __syncthreads();
    const int s = sid[b];
    const int p = atomicAdd(&lc[s], 1);
    __syncthreads();
    if (tid < St) lb[tid] = atomicAdd(&cnt[tid], lc[tid]);
    __syncthreads();
    perm[s * Bt + lb[s] + p] = (unsigned short)b;
    return;
  }

  const int s = bid / 5, m = bid % 5;
  char* Gs = G + s * SKB;

  if (m == 2) {  // Wa3: 128x17 -> direct scatter
    const float* src = Wa3 + s * Ht * At;
    for (int e = tid; e < Ht * At; e += 256) {
      const int k = e / At, n = e - k * At;
      *(unsigned short*)(Gs + OA3 + n * 256 + 2 * k) = f2bf(src[e]);
    }
    return;
  }

  const float* src; int K, off;
  if (m == 0)      { src = Wa1 + s * Dt * Ht; K = 64;  off = OA1; }
  else if (m == 1) { src = Wa2 + s * Ht * Ht; K = 128; off = OA2; }
  else if (m == 3) { src = Wc1 + s * Dt * Ht; K = 64;  off = OC1; }
  else             { src = Wc2 + s * Ht * Ht; K = 128; off = OC2; }
  const int SB = 2 * K;
  const int lsb = (K == 128) ? 8 : 7;
  const int pm = (K == 128) ? 15 : 7;

  unsigned short* lds = (unsigned short*)smem;
  for (int it = 0; it < K / 8; ++it) {
    const int f = (it * 256 + tid) * 4;
    const int k = f >> 7, n0 = f & 127;
    const f32x4 v = *(const f32x4*)(src + f);
#pragma unroll
    for (int j = 0; j < 4; ++j) {
      const int n = n0 + j;
      const int byte = n * SB + ((2 * k) ^ (((n >> 2) & pm) << 4));
      lds[byte >> 1] = f2bf(v[j]);
    }
  }
  __syncthreads();
  const int nbytes = 128 * SB;
  for (int it = 0; it < nbytes / 2048; ++it) {
    const int q = (it * 256 + tid) * 8;
    const int n = q >> lsb, r = q & (SB - 1);
    const unsigned long long v8 =
        *(const unsigned long long*)(smem + n * SB + (r ^ (((n >> 2) & pm) << 4)));
    *(unsigned long long*)(Gs + off + q) = v8;
  }
}

// ---- load macros: explicit register batches to force deep MLP ----
#define LD2(W, i, OFF, t) { \
  const char* wr_ = Gs + (OFF) + ((t) * 16 + m) * 128 + lg * 16; \
  W[i] = *(const bf16x8*)wr_; W[(i) + 1] = *(const bf16x8*)(wr_ + 64); }
#define LD4(W, i, OFF, t) { \
  const char* wr_ = Gs + (OFF) + ((t) * 16 + m) * 256 + lg * 16; \
  W[i] = *(const bf16x8*)wr_;          W[(i) + 1] = *(const bf16x8*)(wr_ + 64); \
  W[(i) + 2] = *(const bf16x8*)(wr_ + 128); W[(i) + 3] = *(const bf16x8*)(wr_ + 192); }

#define STOREH(t, acc, BB) { \
  const f32x4 bb_ = *(const f32x4*)((BB) + (t) * 16 + lg * 4); \
  const f32x4 b2_ = bb_ + bb_; \
  const unsigned lo_ = cvtpk(tanh_fb(acc[0], b2_[0]), tanh_fb(acc[1], b2_[1])); \
  const unsigned hi_ = cvtpk(tanh_fb(acc[2], b2_[2]), tanh_fb(acc[3], b2_[3])); \
  *(unsigned long long*)(hw + ((32 * (t) + 8 * lg) ^ msw)) = \
      (unsigned long long)lo_ | ((unsigned long long)hi_ << 32); }

#define CONS1(W, i, t, BB) { \
  f32x4 a_ = {0.f, 0.f, 0.f, 0.f}; \
  a_ = MFMA(W[i], XB0.v, a_); a_ = MFMA(W[(i) + 1], XB1.v, a_); \
  STOREH(t, a_, BB); }

#define CONS2(W, i, t, BB) { \
  f32x4 a_ = {0.f, 0.f, 0.f, 0.f}; \
  a_ = MFMA(W[i], h0, a_); a_ = MFMA(W[(i) + 1], h1, a_); \
  a_ = MFMA(W[(i) + 2], h2, a_); a_ = MFMA(W[(i) + 3], h3, a_); \
  STOREH(t, a_, BB); }

#define CONSV(W, i, t) { \
  f32x4 a_ = {0.f, 0.f, 0.f, 0.f}; \
  a_ = MFMA(W[i], h0, a_); a_ = MFMA(W[(i) + 1], h1, a_); \
  a_ = MFMA(W[(i) + 2], h2, a_); a_ = MFMA(W[(i) + 3], h3, a_); \
  const f32x4 bb_ = *(const f32x4*)(bc2s + (t) * 16 + lg * 4); \
  const f32x4 b2_ = bb_ + bb_; \
  const f32x4 w3_ = *(const f32x4*)(wc3s + (t) * 16 + lg * 4); \
  vp = __builtin_fmaf(tanh_fb(a_[0], b2_[0]), w3_[0], vp); \
  vp = __builtin_fmaf(tanh_fb(a_[1], b2_[1]), w3_[1], vp); \
  vp = __builtin_fmaf(tanh_fb(a_[2], b2_[2]), w3_[2], vp); \
  vp = __builtin_fmaf(tanh_fb(a_[3], b2_[3]), w3_[3], vp); }

#define READH() \
  const bf16x8 h0 = *(const bf16x8*)(hw + ((0   + 16 * lg) ^ msw)); \
  const bf16x8 h1 = *(const bf16x8*)(hw + ((64  + 16 * lg) ^ msw)); \
  const bf16x8 h2 = *(const bf16x8*)(hw + ((128 + 16 * lg) ^ msw)); \
  const bf16x8 h3 = *(const bf16x8*)(hw + ((192 + 16 * lg) ^ msw)); \
  LGKM0();

// ---------- dispatch 3: swapped-operand MLP; role-split; batched register loads ----------
__global__ __launch_bounds__(256, 4) void k_main(
    const float* __restrict__ obs,
    const float* __restrict__ ba1, const float* __restrict__ ba2,
    const float* __restrict__ ba3, const float* __restrict__ bc1,
    const float* __restrict__ bc2, const float* __restrict__ Wc3,
    const float* __restrict__ bc3,
    const int* __restrict__ cnt, const unsigned short* __restrict__ perm,
    const char* __restrict__ G, float* __restrict__ out) {
  __shared__ char hbuf[16384];   // 4 waves x (16 rows x 256B), wave-private slices

  const int tid = threadIdx.x;
  const int wave = tid >> 6, lane = tid & 63;
  const int m = lane & 15, lg = lane >> 4;
  const int bid = blockIdx.y;

  // ---- tile lookup: in-wave prefix scan over cnt (no dead blocks) ----
  const int c16 = cnt[m];
  const int t16 = (c16 + 63) >> 6;
  int incl = t16;
#pragma unroll
  for (int d = 1; d < 16; d <<= 1) {
    const int o = __shfl_up(incl, d, 16);
    if (m >= d) incl += o;
  }
  const int total = __shfl(incl, 15, 16);
  if (bid >= total) return;
  const int excl = incl - t16;
  const unsigned long long ball = __ballot(excl <= bid);
  const int s = (int)(__popcll(ball) >> 2) - 1;
  const int excl_s = __shfl(excl, s, 16);
  const int cs = __shfl(c16, s, 16);
  const int base = (bid - excl_s) * 64;
  const int cm1 = cs - 1 - base;          // >= 0

  const unsigned short* ps = perm + s * Bt + base;
  const int myrow = ps[min(wave * 16 + m, cm1)];   // chain head: issue ASAP

  const char* Gs = G + s * SKB;
  char* hw = hbuf + wave * 4096 + m * 256;
  const int msw = (m & 7) << 4;

  if (blockIdx.x == 0) {
    // =================== ACTOR ===================
    const float* ba1s = ba1 + s * Ht;
    const float* ba2s = ba2 + s * Ht;
    // L1 weights: all 16 frags into flight (independent of perm/obs chain)
    bf16x8 W0[8], W1[8];
    LD2(W0, 0, OA1, 0) LD2(W0, 2, OA1, 1) LD2(W0, 4, OA1, 2) LD2(W0, 6, OA1, 3)
    LD2(W1, 0, OA1, 4) LD2(W1, 2, OA1, 5) LD2(W1, 4, OA1, 6) LD2(W1, 6, OA1, 7)
    // obs gather (waits myrow; weights already in flight)
    const float* ap = obs + myrow * Dt + lg * 8;
    const f32x4 x0 = *(const f32x4*)(ap);
    const f32x4 x1 = *(const f32x4*)(ap + 4);
    const f32x4 x2 = *(const f32x4*)(ap + 32);
    const f32x4 x3 = *(const f32x4*)(ap + 36);
    union { bf16x8 v; unsigned u[4]; } XB0, XB1;
    XB0.u[0] = cvtpk(x0[0], x0[1]); XB0.u[1] = cvtpk(x0[2], x0[3]);
    XB0.u[2] = cvtpk(x1[0], x1[1]); XB0.u[3] = cvtpk(x1[2], x1[3]);
    XB1.u[0] = cvtpk(x2[0], x2[1]); XB1.u[1] = cvtpk(x2[2], x2[3]);
    XB1.u[2] = cvtpk(x3[0], x3[1]); XB1.u[3] = cvtpk(x3[2], x3[3]);
    // L1 consume
    CONS1(W0, 0, 0, ba1s) CONS1(W0, 2, 1, ba1s)
    CONS1(W0, 4, 2, ba1s) CONS1(W0, 6, 3, ba1s)
    CONS1(W1, 0, 4, ba1s) CONS1(W1, 2, 5, ba1s)
    CONS1(W1, 4, 6, ba1s) CONS1(W1, 6, 7, ba1s)
    LGKM0();
    bf16x8 R[8];                    // L3 weights, prefetched under L2
    {
      READH();                      // L1 output
      bf16x8 P0[8], P1[8];
      LD4(P0, 0, OA2, 0) LD4(P0, 4, OA2, 1)
      LD4(P1, 0, OA2, 2) LD4(P1, 4, OA2, 3)
      CONS2(P0, 0, 0, ba2s) CONS2(P0, 4, 1, ba2s)
      LD4(P0, 0, OA2, 4) LD4(P0, 4, OA2, 5)
      CONS2(P1, 0, 2, ba2s) CONS2(P1, 4, 3, ba2s)
      LD4(P1, 0, OA2, 6) LD4(P1, 4, OA2, 7)
      CONS2(P0, 0, 4, ba2s) CONS2(P0, 4, 5, ba2s)
      LD4(R, 0, OA3, 0) LD4(R, 4, OA3, 1)     // n = m and 16+m rows
      CONS2(P1, 0, 6, ba2s) CONS2(P1, 4, 7, ba2s)
      LGKM0();
    }
    {
      READH();                      // L2 output
      f32x4 a0 = {0.f, 0.f, 0.f, 0.f}, a1 = {0.f, 0.f, 0.f, 0.f};
      a0 = MFMA(R[0], h0, a0); a0 = MFMA(R[1], h1, a0);
      a0 = MFMA(R[2], h2, a0); a0 = MFMA(R[3], h3, a0);
      a1 = MFMA(R[4], h0, a1); a1 = MFMA(R[5], h1, a1);
      a1 = MFMA(R[6], h2, a1); a1 = MFMA(R[7], h3, a1);
      float* orow = out + myrow * At;
#pragma unroll
      for (int i = 0; i < 4; ++i)
        orow[4 * lg + i] = a0[i] + ba3[s * At + 4 * lg + i];
      if (lg == 0) orow[16] = a1[0] + ba3[s * At + 16];
    }
  } else {
    // =================== CRITIC ===================
    const float* bc1s = bc1 + s * Ht;
    const float* bc2s = bc2 + s * Ht;
    const float* wc3s = Wc3 + s * Ht;
    bf16x8 W0[8], W1[8];
    LD2(W0, 0, OC1, 0) LD2(W0, 2, OC1, 1) LD2(W0, 4, OC1, 2) LD2(W0, 6, OC1, 3)
    LD2(W1, 0, OC1, 4) LD2(W1, 2, OC1, 5) LD2(W1, 4, OC1, 6) LD2(W1, 6, OC1, 7)
    const float* ap = obs + myrow * Dt + lg * 8;
    const f32x4 x0 = *(const f32x4*)(ap);
    const f32x4 x1 = *(const f32x4*)(ap + 4);
    const f32x4 x2 = *(const f32x4*)(ap + 32);
    const f32x4 x3 = *(const f32x4*)(ap + 36);
    union { bf16x8 v; unsigned u[4]; } XB0, XB1;
    XB0.u[0] = cvtpk(x0[0], x0[1]); XB0.u[1] = cvtpk(x0[2], x0[3]);
    XB0.u[2] = cvtpk(x1[0], x1[1]); XB0.u[3] = cvtpk(x1[2], x1[3]);
    XB1.u[0] = cvtpk(x2[0], x2[1]); XB1.u[1] = cvtpk(x2[2], x2[3]);
    XB1.u[2] = cvtpk(x3[0], x3[1]); XB1.u[3] = cvtpk(x3[2], x3[3]);
    CONS1(W0, 0, 0, bc1s) CONS1(W0, 2, 1, bc1s)
    CONS1(W0, 4, 2, bc1s) CONS1(W0, 6, 3, bc1s)
    CONS1(W1, 0, 4, bc1s) CONS1(W1, 2, 5, bc1s)
    CONS1(W1, 4, 6, bc1s) CONS1(W1, 6, 7, bc1s)
    LGKM0();
    {
      READH();                      // C1 output (no further hbuf writes below)
      bf16x8 P0[8], P1[8];
      LD4(P0, 0, OC2, 0) LD4(P0, 4, OC2, 1)
      LD4(P1, 0, OC2, 2) LD4(P1, 4, OC2, 3)
      float vp = 0.f;
      CONSV(P0, 0, 0) CONSV(P0, 4, 1)
      LD4(P0, 0, OC2, 4) LD4(P0, 4, OC2, 5)
      CONSV(P1, 0, 2) CONSV(P1, 4, 3)
      LD4(P1, 0, OC2, 6) LD4(P1, 4, OC2, 7)
      CONSV(P0, 0, 4) CONSV(P0, 4, 5)
      CONSV(P1, 0, 6) CONSV(P1, 4, 7)
      vp += __shfl_xor(vp, 16);
      vp += __shfl_xor(vp, 32);
      if (lane < 16) out[Bt * At + myrow] = vp + bc3[s];
    }
  }
}

extern "C" void kernel_launch(void* const* d_in, const int* in_sizes, int n_in,
                              void* d_out, int out_size, void* d_ws, size_t ws_size,
                              hipStream_t stream) {
  const float* obs = (const float*)d_in[0];
  const int* sid   = (const int*)d_in[1];
  const float* Wa1 = (const float*)d_in[2];
  const float* ba1 = (const float*)d_in[3];
  const float* Wa2 = (const float*)d_in[4];
  const float* ba2 = (const float*)d_in[5];
  const float* Wa3 = (const float*)d_in[6];
  const float* ba3 = (const float*)d_in[7];
  const float* Wc1 = (const float*)d_in[8];
  const float* bc1 = (const float*)d_in[9];
  const float* Wc2 = (const float*)d_in[10];
  const float* bc2 = (const float*)d_in[11];
  const float* Wc3 = (const float*)d_in[12];
  const float* bc3 = (const float*)d_in[13];
  float* out = (float*)d_out;
  char* ws = (char*)d_ws;

  int* cnt = (int*)(ws + CNT_OFF);
  unsigned short* perm = (unsigned short*)(ws + PERM_OFF);
  char* G = ws + WB_OFF;

  hipMemsetAsync(cnt, 0, St * sizeof(int), stream);
  k_fused<<<dim3(208), dim3(256), 0, stream>>>(sid, perm, cnt, Wa1, Wa2, Wa3, Wc1, Wc2, G);
  k_main<<<dim3(2, 528), dim3(256), 0, stream>>>(
      obs, ba1, ba2, ba3, bc1, bc2, Wc3, bc3, cnt, perm, G, out);
}

// Round 7
// 33.016 us; speedup vs baseline: 1.8672x; 1.6411x over previous
//
#include <hip/hip_runtime.h>

#define Bt 32768
#define Dt 64
#define St 16
#define Ht 128
#define At 17

typedef __attribute__((ext_vector_type(8))) short bf16x8;
typedef __attribute__((ext_vector_type(4))) float f32x4;

// ---- workspace layout (bytes) ----
#define CNT_OFF   0          // int[16]
#define PERM_OFF  128        // u16 [S][B]  (1 MiB)
#define WB_OFF    1049600    // bf16 transposed weight images [n][k], XOR-swizzled
#define OA1 0        // Wa1^T: 128 rows x 128B (K=64)
#define OA2 16384    // Wa2^T: 128 rows x 256B (K=128)
#define OA3 49152    // Wa3^T: 32-row region, rows >=17 unused garbage
#define OC1 57344    // Wc1^T
#define OC2 73728    // Wc2^T
#define SKB 106496   // per-skill stride

__device__ __forceinline__ unsigned short f2bf(float f) {
  union { float f; unsigned u; } v; v.f = f;
  unsigned r = v.u + 0x7FFFu + ((v.u >> 16) & 1u);  // RNE
  return (unsigned short)(r >> 16);
}

// packed f32x2 -> bf16x2 in one VALU op (gfx950 v_cvt_pk_bf16_f32; src0 -> lo)
__device__ __forceinline__ unsigned cvtpk(float a, float b) {
  unsigned r;
  asm("v_cvt_pk_bf16_f32 %0, %1, %2" : "=v"(r) : "v"(a), "v"(b));
  return r;
}

// tanh(acc + bias) with b2 = 2*bias precomputed: fma, exp, add, rcp, fma
__device__ __forceinline__ float tanh_fb(float acc, float b2) {
  const float t = __expf(__builtin_fmaf(acc, 2.0f, b2));  // inf-safe
  const float r = __builtin_amdgcn_rcpf(t + 1.0f);
  return __builtin_fmaf(-2.0f, r, 1.0f);
}

__device__ __forceinline__ f32x4 MFMA(bf16x8 a, bf16x8 b, f32x4 c) {
  return __builtin_amdgcn_mfma_f32_16x16x32_bf16(a, b, c, 0, 0, 0);
}

#define LGKM0() asm volatile("s_waitcnt lgkmcnt(0)" ::: "memory")

// async global->LDS, 16B/lane (R1-verified usage)
__device__ __forceinline__ void ldsload16(const char* g, char* l) {
  __builtin_amdgcn_global_load_lds(
      (const __attribute__((address_space(1))) unsigned int*)g,
      (__attribute__((address_space(3))) unsigned int*)l, 16, 0, 0);
}
// linear copy of pre-swizzled image: dest = wave-uniform base + lane*16
__device__ __forceinline__ void stageW(const char* g, char* lds, int bytes,
                                       int wave, int lane) {
  for (int c = wave * 1024; c < bytes; c += 4096)
    ldsload16(g + c + lane * 16, lds + c);
}

// ---------- dispatch 2: fused bucket (blocks 80..207) + weight prep (blocks 0..79) ----------
// prep emits bf16 [n][k] images with byte swizzle: image[n][r] = W^T[n][(r ^ ((n&7)<<4))/2]
__global__ __launch_bounds__(256) void k_fused(
    const int* __restrict__ sid, unsigned short* __restrict__ perm,
    int* __restrict__ cnt,
    const float* __restrict__ Wa1, const float* __restrict__ Wa2,
    const float* __restrict__ Wa3, const float* __restrict__ Wc1,
    const float* __restrict__ Wc2, char* __restrict__ G) {
  __shared__ __align__(16) char smem[32768];
  const int tid = threadIdx.x;
  const int bid = blockIdx.x;

  if (bid >= 80) {
    int* lc = (int*)smem;
    int* lb = lc + St;
    const int b = (bid - 80) * 256 + tid;
    if (tid < St) lc[tid] = 0;
    __syncthreads();
    const int s = sid[b];
    const int p = atomicAdd(&lc[s], 1);
    __syncthreads();
    if (tid < St) lb[tid] = atomicAdd(&cnt[tid], lc[tid]);
    __syncthreads();
    perm[s * Bt + lb[s] + p] = (unsigned short)b;
    return;
  }

  const int s = bid / 5, mm = bid % 5;
  char* Gs = G + s * SKB;

  if (mm == 2) {  // Wa3: 128x17 -> direct swizzled scatter
    const float* src = Wa3 + s * Ht * At;
    for (int e = tid; e < Ht * At; e += 256) {
      const int k = e / At, n = e - k * At;
      *(unsigned short*)(Gs + OA3 + n * 256 + ((2 * k) ^ ((n & 7) << 4))) =
          f2bf(src[e]);
    }
    return;
  }

  const float* src; int K, off;
  if (mm == 0)      { src = Wa1 + s * Dt * Ht; K = 64;  off = OA1; }
  else if (mm == 1) { src = Wa2 + s * Ht * Ht; K = 128; off = OA2; }
  else if (mm == 3) { src = Wc1 + s * Dt * Ht; K = 64;  off = OC1; }
  else              { src = Wc2 + s * Ht * Ht; K = 128; off = OC2; }
  const int SB = 2 * K;
  const int lsb = (K == 128) ? 8 : 7;
  const int pm = (K == 128) ? 15 : 7;   // prep-internal bank-spread swizzle

  unsigned short* lds = (unsigned short*)smem;
  // phase 1: coalesced f32x4 reads along n; transposed, P_n-swizzled LDS writes
  for (int it = 0; it < K / 8; ++it) {
    const int f = (it * 256 + tid) * 4;
    const int k = f >> 7, n0 = f & 127;
    const f32x4 v = *(const f32x4*)(src + f);
#pragma unroll
    for (int j = 0; j < 4; ++j) {
      const int n = n0 + j;
      const int byte = n * SB + ((2 * k) ^ (((n >> 2) & pm) << 4));
      lds[byte >> 1] = f2bf(v[j]);
    }
  }
  __syncthreads();
  // phase 2: coalesced 8B writes of the OUTPUT-swizzled image:
  // out byte (n,r) holds element 2k = r ^ ((n&7)<<4); fetch via both XORs
  const int nbytes = 128 * SB;
  for (int it = 0; it < nbytes / 2048; ++it) {
    const int q = (it * 256 + tid) * 8;
    const int n = q >> lsb, r = q & (SB - 1);
    const int srcoff = (r ^ ((n & 7) << 4)) ^ (((n >> 2) & pm) << 4);
    const unsigned long long v8 =
        *(const unsigned long long*)(smem + n * SB + srcoff);
    *(unsigned long long*)(Gs + off + q) = v8;
  }
}

// swizzled weight-fragment read from LDS (row n, n&7 == m&7 always here)
#define WRD(BASE, SRW, N, C) \
  (*(const bf16x8*)((BASE) + (N) * (SRW) + (((C) + lg * 16) ^ msw)))

#define STOREH(HW, t, acc, BB) { \
  const f32x4 bb_ = *(const f32x4*)((BB) + (t) * 16 + lg * 4); \
  const f32x4 b2_ = bb_ + bb_; \
  const unsigned lo_ = cvtpk(tanh_fb(acc[0], b2_[0]), tanh_fb(acc[1], b2_[1])); \
  const unsigned hi_ = cvtpk(tanh_fb(acc[2], b2_[2]), tanh_fb(acc[3], b2_[3])); \
  *(unsigned long long*)((HW) + ((32 * (t) + 8 * lg) ^ msw)) = \
      (unsigned long long)lo_ | ((unsigned long long)hi_ << 32); }

// ---------- dispatch 3: LDS-staged per-skill MLP; 128 rows/block, 32 rows/wave ----------
__global__ __launch_bounds__(256, 2) void k_main(
    const float* __restrict__ obs,
    const float* __restrict__ ba1, const float* __restrict__ ba2,
    const float* __restrict__ ba3, const float* __restrict__ bc1,
    const float* __restrict__ bc2, const float* __restrict__ Wc3,
    const float* __restrict__ bc3,
    const int* __restrict__ cnt, const unsigned short* __restrict__ perm,
    const char* __restrict__ G, float* __restrict__ out) {
  __shared__ __align__(16) char wbuf[40960];   // staged weights (+OA3 tail region)
  __shared__ __align__(16) char hbuf[32768];   // 128 rows x 256B, wave-private rows

  const int tid = threadIdx.x;
  const int wave = tid >> 6, lane = tid & 63;
  const int m = lane & 15, lg = lane >> 4;
  const int bid = blockIdx.y;
  const bool actor = (blockIdx.x == 0);

  // ---- tile lookup (tile = 128 rows): in-wave prefix scan over cnt ----
  const int c16 = cnt[m];
  const int t16 = (c16 + 127) >> 7;
  int incl = t16;
#pragma unroll
  for (int d = 1; d < 16; d <<= 1) {
    const int o = __shfl_up(incl, d, 16);
    if (m >= d) incl += o;
  }
  const int total = __shfl(incl, 15, 16);
  if (bid >= total) return;
  const int excl = incl - t16;
  const unsigned long long ball = __ballot(excl <= bid);
  const int s = (int)(__popcll(ball) >> 2) - 1;
  const int excl_s = __shfl(excl, s, 16);
  const int cs = __shfl(c16, s, 16);
  const int base = (bid - excl_s) * 128;
  const int cm1 = cs - 1 - base;          // >= 0

  const unsigned short* ps = perm + s * Bt + base;
  const int row0 = ps[min(wave * 32 + m, cm1)];        // rowset 0
  const int row1 = ps[min(wave * 32 + 16 + m, cm1)];   // rowset 1

  const char* Gs = G + s * SKB;

  // obs gathers first (oldest in vmcnt queue -> pack need not wait on staging)
  const float* ap0 = obs + row0 * Dt + lg * 8;
  const float* ap1 = obs + row1 * Dt + lg * 8;
  const f32x4 x0 = *(const f32x4*)(ap0);
  const f32x4 x1 = *(const f32x4*)(ap0 + 4);
  const f32x4 x2 = *(const f32x4*)(ap0 + 32);
  const f32x4 x3 = *(const f32x4*)(ap0 + 36);
  const f32x4 y0 = *(const f32x4*)(ap1);
  const f32x4 y1 = *(const f32x4*)(ap1 + 4);
  const f32x4 y2 = *(const f32x4*)(ap1 + 32);
  const f32x4 y3 = *(const f32x4*)(ap1 + 36);

  stageW(Gs + (actor ? OA1 : OC1), wbuf, 16384, wave, lane);

  union { bf16x8 v; unsigned u[4]; } XB0, XB1, XB2, XB3;
  XB0.u[0] = cvtpk(x0[0], x0[1]); XB0.u[1] = cvtpk(x0[2], x0[3]);
  XB0.u[2] = cvtpk(x1[0], x1[1]); XB0.u[3] = cvtpk(x1[2], x1[3]);
  XB1.u[0] = cvtpk(x2[0], x2[1]); XB1.u[1] = cvtpk(x2[2], x2[3]);
  XB1.u[2] = cvtpk(x3[0], x3[1]); XB1.u[3] = cvtpk(x3[2], x3[3]);
  XB2.u[0] = cvtpk(y0[0], y0[1]); XB2.u[1] = cvtpk(y0[2], y0[3]);
  XB2.u[2] = cvtpk(y1[0], y1[1]); XB2.u[3] = cvtpk(y1[2], y1[3]);
  XB3.u[0] = cvtpk(y2[0], y2[1]); XB3.u[1] = cvtpk(y2[2], y2[3]);
  XB3.u[2] = cvtpk(y3[0], y3[1]); XB3.u[3] = cvtpk(y3[2], y3[3]);

  char* hw0 = hbuf + (wave * 32 + m) * 256;
  char* hw1 = hw0 + 4096;                 // +16 rows
  const int msw = (m & 7) << 4;

  __syncthreads();                        // layer-1 weights staged

  // ================= layer 1 (K=64): weight frag read once, 2 MFMAs =================
  {
    const float* B1 = (actor ? ba1 : bc1) + s * Ht;
#pragma unroll
    for (int nt = 0; nt < 8; ++nt) {
      const bf16x8 a0 = WRD(wbuf, 128, nt * 16 + m, 0);
      const bf16x8 a1 = WRD(wbuf, 128, nt * 16 + m, 64);
      f32x4 acc0 = {0.f, 0.f, 0.f, 0.f}, acc1 = {0.f, 0.f, 0.f, 0.f};
      acc0 = MFMA(a0, XB0.v, acc0); acc0 = MFMA(a1, XB1.v, acc0);
      acc1 = MFMA(a0, XB2.v, acc1); acc1 = MFMA(a1, XB3.v, acc1);
      STOREH(hw0, nt, acc0, B1);
      STOREH(hw1, nt, acc1, B1);
    }
  }
  __syncthreads();                        // all waves done reading wbuf
  stageW(Gs + (actor ? OA2 : OC2), wbuf, 32768, wave, lane);
  if (actor) stageW(Gs + OA3, wbuf + 32768, 8192, wave, lane);
  LGKM0();                                // hbuf writes landed (own-wave ds order)
  const bf16x8 h0 = *(const bf16x8*)(hw0 + ((0   + 16 * lg) ^ msw));
  const bf16x8 h1 = *(const bf16x8*)(hw0 + ((64  + 16 * lg) ^ msw));
  const bf16x8 h2 = *(const bf16x8*)(hw0 + ((128 + 16 * lg) ^ msw));
  const bf16x8 h3 = *(const bf16x8*)(hw0 + ((192 + 16 * lg) ^ msw));
  const bf16x8 g0 = *(const bf16x8*)(hw1 + ((0   + 16 * lg) ^ msw));
  const bf16x8 g1 = *(const bf16x8*)(hw1 + ((64  + 16 * lg) ^ msw));
  const bf16x8 g2 = *(const bf16x8*)(hw1 + ((128 + 16 * lg) ^ msw));
  const bf16x8 g3 = *(const bf16x8*)(hw1 + ((192 + 16 * lg) ^ msw));
  __syncthreads();                        // layer-2 (+L3) weights staged

  if (actor) {
    // ================= actor layer 2 (K=128) =================
    const float* B2 = ba2 + s * Ht;
#pragma unroll
    for (int nt = 0; nt < 8; ++nt) {
      const int n = nt * 16 + m;
      const bf16x8 w0 = WRD(wbuf, 256, n, 0);
      const bf16x8 w1 = WRD(wbuf, 256, n, 64);
      const bf16x8 w2 = WRD(wbuf, 256, n, 128);
      const bf16x8 w3 = WRD(wbuf, 256, n, 192);
      f32x4 acc0 = {0.f, 0.f, 0.f, 0.f}, acc1 = {0.f, 0.f, 0.f, 0.f};
      acc0 = MFMA(w0, h0, acc0); acc0 = MFMA(w1, h1, acc0);
      acc0 = MFMA(w2, h2, acc0); acc0 = MFMA(w3, h3, acc0);
      acc1 = MFMA(w0, g0, acc1); acc1 = MFMA(w1, g1, acc1);
      acc1 = MFMA(w2, g2, acc1); acc1 = MFMA(w3, g3, acc1);
      STOREH(hw0, nt, acc0, B2);
      STOREH(hw1, nt, acc1, B2);
    }
    LGKM0();
    // ================= actor layer 3 -> logits =================
    const bf16x8 H0 = *(const bf16x8*)(hw0 + ((0   + 16 * lg) ^ msw));
    const bf16x8 H1 = *(const bf16x8*)(hw0 + ((64  + 16 * lg) ^ msw));
    const bf16x8 H2 = *(const bf16x8*)(hw0 + ((128 + 16 * lg) ^ msw));
    const bf16x8 H3 = *(const bf16x8*)(hw0 + ((192 + 16 * lg) ^ msw));
    const bf16x8 G0 = *(const bf16x8*)(hw1 + ((0   + 16 * lg) ^ msw));
    const bf16x8 G1 = *(const bf16x8*)(hw1 + ((64  + 16 * lg) ^ msw));
    const bf16x8 G2 = *(const bf16x8*)(hw1 + ((128 + 16 * lg) ^ msw));
    const bf16x8 G3 = *(const bf16x8*)(hw1 + ((192 + 16 * lg) ^ msw));
    const char* w3b = wbuf + 32768;
    const bf16x8 e0 = WRD(w3b, 256, m, 0);
    const bf16x8 e1 = WRD(w3b, 256, m, 64);
    const bf16x8 e2 = WRD(w3b, 256, m, 128);
    const bf16x8 e3 = WRD(w3b, 256, m, 192);
    const bf16x8 f0 = WRD(w3b, 256, 16 + m, 0);
    const bf16x8 f1 = WRD(w3b, 256, 16 + m, 64);
    const bf16x8 f2 = WRD(w3b, 256, 16 + m, 128);
    const bf16x8 f3 = WRD(w3b, 256, 16 + m, 192);
    f32x4 p0 = {0.f, 0.f, 0.f, 0.f}, p1 = {0.f, 0.f, 0.f, 0.f};
    f32x4 q0 = {0.f, 0.f, 0.f, 0.f}, q1 = {0.f, 0.f, 0.f, 0.f};
    p0 = MFMA(e0, H0, p0); p0 = MFMA(e1, H1, p0);
    p0 = MFMA(e2, H2, p0); p0 = MFMA(e3, H3, p0);
    p1 = MFMA(f0, H0, p1); p1 = MFMA(f1, H1, p1);
    p1 = MFMA(f2, H2, p1); p1 = MFMA(f3, H3, p1);
    q0 = MFMA(e0, G0, q0); q0 = MFMA(e1, G1, q0);
    q0 = MFMA(e2, G2, q0); q0 = MFMA(e3, G3, q0);
    q1 = MFMA(f0, G0, q1); q1 = MFMA(f1, G1, q1);
    q1 = MFMA(f2, G2, q1); q1 = MFMA(f3, G3, q1);
    const float* ba3s = ba3 + s * At;
    float* o0 = out + row0 * At;
    float* o1 = out + row1 * At;
#pragma unroll
    for (int i = 0; i < 4; ++i) {               // n = 4lg+i in 0..15
      o0[4 * lg + i] = p0[i] + ba3s[4 * lg + i];
      o1[4 * lg + i] = q0[i] + ba3s[4 * lg + i];
    }
    if (lg == 0) {                              // n = 16
      o0[16] = p1[0] + ba3s[16];
      o1[16] = q1[0] + ba3s[16];
    }
  } else {
    // ================= critic layer 2 + value =================
    const float* B2 = bc2 + s * Ht;
    const float* w3s = Wc3 + s * Ht;
    float vp0 = 0.f, vp1 = 0.f;
#pragma unroll
    for (int nt = 0; nt < 8; ++nt) {
      const int n = nt * 16 + m;
      const bf16x8 w0 = WRD(wbuf, 256, n, 0);
      const bf16x8 w1 = WRD(wbuf, 256, n, 64);
      const bf16x8 w2 = WRD(wbuf, 256, n, 128);
      const bf16x8 w3 = WRD(wbuf, 256, n, 192);
      f32x4 acc0 = {0.f, 0.f, 0.f, 0.f}, acc1 = {0.f, 0.f, 0.f, 0.f};
      acc0 = MFMA(w0, h0, acc0); acc0 = MFMA(w1, h1, acc0);
      acc0 = MFMA(w2, h2, acc0); acc0 = MFMA(w3, h3, acc0);
      acc1 = MFMA(w0, g0, acc1); acc1 = MFMA(w1, g1, acc1);
      acc1 = MFMA(w2, g2, acc1); acc1 = MFMA(w3, g3, acc1);
      const f32x4 bb = *(const f32x4*)(B2 + nt * 16 + lg * 4);
      const f32x4 b2 = bb + bb;
      const f32x4 wv = *(const f32x4*)(w3s + nt * 16 + lg * 4);
#pragma unroll
      for (int i = 0; i < 4; ++i) {
        vp0 = __builtin_fmaf(tanh_fb(acc0[i], b2[i]), wv[i], vp0);
        vp1 = __builtin_fmaf(tanh_fb(acc1[i], b2[i]), wv[i], vp1);
      }
    }
    vp0 += __shfl_xor(vp0, 16); vp0 += __shfl_xor(vp0, 32);
    vp1 += __shfl_xor(vp1, 16); vp1 += __shfl_xor(vp1, 32);
    if (lane < 16) {
      const float b3 = bc3[s];
      out[Bt * At + row0] = vp0 + b3;
      out[Bt * At + row1] = vp1 + b3;
    }
  }
}

extern "C" void kernel_launch(void* const* d_in, const int* in_sizes, int n_in,
                              void* d_out, int out_size, void* d_ws, size_t ws_size,
                              hipStream_t stream) {
  const float* obs = (const float*)d_in[0];
  const int* sid   = (const int*)d_in[1];
  const float* Wa1 = (const float*)d_in[2];
  const float* ba1 = (const float*)d_in[3];
  const float* Wa2 = (const float*)d_in[4];
  const float* ba2 = (const float*)d_in[5];
  const float* Wa3 = (const float*)d_in[6];
  const float* ba3 = (const float*)d_in[7];
  const float* Wc1 = (const float*)d_in[8];
  const float* bc1 = (const float*)d_in[9];
  const float* Wc2 = (const float*)d_in[10];
  const float* bc2 = (const float*)d_in[11];
  const float* Wc3 = (const float*)d_in[12];
  const float* bc3 = (const float*)d_in[13];
  float* out = (float*)d_out;
  char* ws = (char*)d_ws;

  int* cnt = (int*)(ws + CNT_OFF);
  unsigned short* perm = (unsigned short*)(ws + PERM_OFF);
  char* G = ws + WB_OFF;

  hipMemsetAsync(cnt, 0, St * sizeof(int), stream);
  k_fused<<<dim3(208), dim3(256), 0, stream>>>(sid, perm, cnt, Wa1, Wa2, Wa3, Wc1, Wc2, G);
  k_main<<<dim3(2, 272), dim3(256), 0, stream>>>(
      obs, ba1, ba2, ba3, bc1, bc2, Wc3, bc3, cnt, perm, G, out);
}